// Round 9
// baseline (542.338 us; speedup 1.0000x reference)
//
#include <hip/hip_runtime.h>
#include <hip/hip_bf16.h>

#define NROWS 100000
#define NH 8
#define RPC 1568     // k1 rows per chunk (64 chunks)
#define NSUB 49      // 32-row subtiles per chunk
#define NCH1 64      // partial-kTv slices (one per k1 row-chunk)

typedef short s16x8 __attribute__((ext_vector_type(8)));
typedef float f32x4 __attribute__((ext_vector_type(4)));
typedef unsigned short u16;

__device__ __forceinline__ u16 f2bf(float f) {
  union { float f; unsigned u; } x; x.f = f;
  unsigned r = (x.u + 0x7FFFu + ((x.u >> 16) & 1u)) >> 16;
  return (u16)r;
}
__device__ __forceinline__ float bf2f(u16 b) {
  union { unsigned u; float f; } x; x.u = ((unsigned)b) << 16;
  return x.f;
}
// HW packed f32->bf16 (RNE, 1 VALU inst for 2 elems; bit-identical to f2bf
// for finite inputs).  D[15:0]=cvt(S0), D[31:16]=cvt(S1).
__device__ __forceinline__ unsigned cvt2bf(float lo, float hi) {
  unsigned r;
  asm("v_cvt_pk_bf16_f32 %0, %1, %2" : "=v"(r) : "v"(lo), "v"(hi));
  return r;
}
__device__ __forceinline__ ushort4 cvt4bf(float a, float b, float c, float d) {
  union { unsigned u[2]; ushort4 s; } r;
  r.u[0] = cvt2bf(a, b);
  r.u[1] = cvt2bf(c, d);
  return r.s;
}

// Workgroup barrier WITHOUT vmcnt(0) drain: LDS visibility only (r8-verified).
__device__ __forceinline__ void wg_barrier_lds() {
  asm volatile("s_waitcnt lgkmcnt(0)" ::: "memory");
  __builtin_amdgcn_s_barrier();
  asm volatile("" ::: "memory");
}

// ---------------------------------------------------------------------------
// Kernel 0: pack W to bf16 MFMA A-fragments.
// Frag id = ((h*2+c2)*48 + s)*64 + lane.  s<32: qk tile t=s>>3, ks=s&7
// (Wq if c2==0 else Wk, col=t*16+(lane&15)); s>=32: v tile tv=(s>>3)-4,
// col = c2*32 + tv*16 + (lane&15).  Elems: k = ks*32 + (lane>>4)*8 + j.
// ---------------------------------------------------------------------------
__global__ __launch_bounds__(256) void k0_pack(
    const float* __restrict__ Wq, const float* __restrict__ Wk,
    const float* __restrict__ Wv, u16* __restrict__ Wp)
{
  int t = blockIdx.x * 256 + threadIdx.x;   // 0..49151
  int lane = t & 63;
  int rest = t >> 6;
  int s = rest % 48;
  int hc = rest / 48;
  int c2 = hc & 1, h = hc >> 1;
  int ml = lane & 15, sgk = lane >> 4;
  const float* W; int col, ks;
  if (s < 32) { int tl = s >> 3; ks = s & 7; W = c2 ? Wk : Wq; col = tl * 16 + ml; }
  else        { int tv = (s >> 3) - 4; ks = s & 7; W = Wv; col = c2 * 32 + tv * 16 + ml; }
  int k0 = ks * 32 + sgk * 8;
  u16 o[8];
#pragma unroll
  for (int j = 0; j < 8; j++)
    o[j] = f2bf(W[((size_t)h * 256 + k0 + j) * 64 + col]);
  ushort4* dst = (ushort4*)(Wp + (size_t)t * 8);
  dst[0] = make_ushort4(o[0], o[1], o[2], o[3]);
  dst[1] = make_ushort4(o[4], o[5], o[6], o[7]);
}

// ---------------------------------------------------------------------------
// Kernel 1 (fused kTv, attempt 3): persistent per-head blocks.
// Grid 512 = 8 heads x 64 row-chunks, blockIdx = rc + 64*h.
// W(q|k) resident in regs; W(v) in LDS.  32-row subtiles, x prefetched one
// subtile ahead.  phi_k NEVER stored to HBM: per-block partial kTv[64][64] +
// sum_k[64] are MFMA-accumulated.  Fragments are gathered with plain-C
// scalar LDS reads FROM THE EXISTING stq/stv staging (no extra epilogue
// writes — r2's failure; no asm fences — r3's failure), placed at the top
// of the NEXT iteration where they overlap x-load latency and interleave
// with the 48 main MFMAs.  stq/stv double-buffered: reads of buf[s-1] are
// separated from its next overwrite (epilogue s+1) by bar1(s)+bar2(s).
// Fragment values are element-identical to round 2's harness-PASSED tks/tvs
// fragments: af[j]=phi_k[sg*8+j][wv*16+m], bfv[dcb][j]=v[sg*8+j][dcb*16+m].
// ---------------------------------------------------------------------------
__global__ __launch_bounds__(256, 2) void k1_gemm_phi(
    const float* __restrict__ x, const u16* __restrict__ Wp,
    const float* __restrict__ bq, const float* __restrict__ bk,
    const float* __restrict__ bv, const float* __restrict__ nsc,
    u16* __restrict__ phi_q, u16* __restrict__ vout, float* __restrict__ P)
{
  __shared__ u16 xs[32 * 256];        // 16 KB, chunk-swizzled
  __shared__ u16 vws[32 * 64 * 8];    // 32 KB, v W-fragments
  __shared__ u16 stq[2][4 * 16 * 72]; // 18432 B, q/k staging, dbuf
  __shared__ u16 stv[2][32 * 72];     // 9216 B, v staging, dbuf
  __shared__ float biasl[192];        // [q|k|v]

  const int tid = threadIdx.x;
  const int wv = tid >> 6, lane = tid & 63;
  const int c2 = wv & 1, rg = wv >> 1;
  const int m = lane & 15, sg = lane >> 4;
  const int rc = blockIdx.x & 63, h = blockIdx.x >> 6;
  const int n0 = rc * RPC;

  if (tid < 192) {
    const float* bp = tid < 64 ? bq : (tid < 128 ? bk : bv);
    biasl[tid] = bp[h * 64 + (tid & 63)];
  }

  // resident qk W fragments: 32 x s16x8
  const u16* wb = Wp + (size_t)(h * 2 + c2) * (48 * 64 * 8);
  s16x8 wq[4][8];
#pragma unroll
  for (int t = 0; t < 4; t++)
#pragma unroll
    for (int ks = 0; ks < 8; ks++)
      wq[t][ks] = *(const s16x8*)(wb + ((t * 8 + ks) * 64 + lane) * 8);

  // v W fragments -> LDS (tiles 0..3 across both c2 regions)
#pragma unroll
  for (int i2 = 0; i2 < 8; i2++) {
    int u = tid + i2 * 256;           // 0..2047 = (tl*8+ks)*64 + ln
    int tl = u >> 9, ks = (u >> 6) & 7, ln = u & 63;
    const u16* src = Wp + ((size_t)(h * 2 + (tl >> 1)) * 48 + 32 + (tl & 1) * 8 + ks) * (64 * 8)
                     + (size_t)ln * 8;
    *(s16x8*)(vws + (size_t)u * 8) = *(const s16x8*)src;
  }

  // stage subtile 0
#pragma unroll
  for (int i = 0; i < 4; i++) {
    int cu = tid + i * 256;
    int row = cu >> 5, c = cu & 31;
    int n = n0 + row; if (n >= NROWS) n = NROWS - 1;
    const float* src = x + (size_t)n * 256 + c * 8;
    float4 f0 = *(const float4*)src;
    float4 f1 = *(const float4*)(src + 4);
    union { unsigned u[4]; s16x8 v; } pk;
    pk.u[0] = cvt2bf(f0.x, f0.y);
    pk.u[1] = cvt2bf(f0.z, f0.w);
    pk.u[2] = cvt2bf(f1.x, f1.y);
    pk.u[3] = cvt2bf(f1.z, f1.w);
    *(s16x8*)(xs + row * 256 + ((c ^ (row & 7)) * 8)) = pk.v;
  }
  __syncthreads();

  const float inv_denom = 1.0f / (fabsf(nsc[0]) + 1e-6f);
  u16* const xbase = xs + (rg * 16 + m) * 256;
  const int sw = m & 7;

  // partial kTv accumulators: wave wv owns mc-block wv*16..+15, 4 dc-blocks
  f32x4 kacc[4];
#pragma unroll
  for (int t = 0; t < 4; t++) kacc[t] = (f32x4){0.f, 0.f, 0.f, 0.f};
  f32x4 ksum = (f32x4){0.f, 0.f, 0.f, 0.f};
  s16x8 onesf;
#pragma unroll
  for (int j = 0; j < 8; j++) onesf[j] = (m == 0) ? (short)0x3F80 : (short)0;

  // Gather + accumulate kTv for staged subtile in buffer pbuf.
  // phi_k[row][ch] lives in stq[pbuf] wave-region (1 if row<16 else 3) at
  // rl*72 + ((ch>>4 + rl)&3)*16 + (ch&15), rl=row&15 (writer swizzle inverted).
  // v[row][ch] in stv[pbuf] at row*72 + ((ch>>4 + row)&3)*16 + (ch&15).
  // Plain C reads -> compiler schedules + inserts counted lgkmcnt.
#define KTV_ACC(pbuf)                                                        \
  {                                                                          \
    const u16* sqs = stq[pbuf] + ((sg < 2) ? 1 : 3) * 1152;                  \
    const u16* svb = stv[pbuf];                                              \
    short afe[8];                                                            \
    _Pragma("unroll")                                                        \
    for (int j = 0; j < 8; j++) {                                            \
      int rl = (sg * 8 + j) & 15;                                            \
      afe[j] = (short)sqs[rl * 72 + (((wv + rl) & 3) << 4) + m];             \
    }                                                                        \
    s16x8 af = {afe[0], afe[1], afe[2], afe[3], afe[4], afe[5], afe[6], afe[7]}; \
    _Pragma("unroll")                                                        \
    for (int dcb = 0; dcb < 4; dcb++) {                                      \
      short be[8];                                                           \
      _Pragma("unroll")                                                      \
      for (int j = 0; j < 8; j++) {                                          \
        int row = sg * 8 + j;                                                \
        be[j] = (short)svb[row * 72 + (((dcb + row) & 3) << 4) + m];         \
      }                                                                      \
      s16x8 bv8 = {be[0], be[1], be[2], be[3], be[4], be[5], be[6], be[7]};  \
      kacc[dcb] = __builtin_amdgcn_mfma_f32_16x16x32_bf16(af, bv8, kacc[dcb], 0, 0, 0); \
    }                                                                        \
    ksum = __builtin_amdgcn_mfma_f32_16x16x32_bf16(af, onesf, ksum, 0, 0, 0); \
  }

  for (int s = 0; s < NSUB; s++) {
    const int buf = s & 1;
    // issue x loads for s+1 (regs; consumed after the barrier)
    float4 xl[8];
    if (s + 1 < NSUB) {
      int nb = n0 + (s + 1) * 32;
#pragma unroll
      for (int i = 0; i < 4; i++) {
        int cu = tid + i * 256;
        int row = cu >> 5, c = cu & 31;
        int n = nb + row; if (n >= NROWS) n = NROWS - 1;
        const float* src = x + (size_t)n * 256 + c * 8;
        xl[i * 2]     = *(const float4*)src;
        xl[i * 2 + 1] = *(const float4*)(src + 4);
      }
    }

    // kTv for PREVIOUS subtile: overlaps x-load latency + main MFMAs below
    if (s > 0 && n0 + (s - 1) * 32 < NROWS) KTV_ACC(buf ^ 1);

    // MFMA: 4 qk tiles (resident W) + 2 v tiles (LDS W)
    f32x4 aq[4], av[2];
#pragma unroll
    for (int t = 0; t < 4; t++) aq[t] = (f32x4){0.f, 0.f, 0.f, 0.f};
    av[0] = (f32x4){0.f, 0.f, 0.f, 0.f};
    av[1] = (f32x4){0.f, 0.f, 0.f, 0.f};
#pragma unroll
    for (int ks = 0; ks < 8; ks++) {
      s16x8 bf = *(const s16x8*)(xbase + (((ks * 4 + sg) ^ sw) * 8));
#pragma unroll
      for (int t = 0; t < 4; t++)
        aq[t] = __builtin_amdgcn_mfma_f32_16x16x32_bf16(wq[t][ks], bf, aq[t], 0, 0, 0);
      s16x8 vw0 = *(const s16x8*)(vws + (((c2 * 2 + 0) * 8 + ks) * 64 + lane) * 8);
      s16x8 vw1 = *(const s16x8*)(vws + (((c2 * 2 + 1) * 8 + ks) * 64 + lane) * 8);
      av[0] = __builtin_amdgcn_mfma_f32_16x16x32_bf16(vw0, bf, av[0], 0, 0, 0);
      av[1] = __builtin_amdgcn_mfma_f32_16x16x32_bf16(vw1, bf, av[1], 0, 0, 0);
    }

    // epilogue: bias + phi + in-wave norm (row = rg*16+m, ch = t*16+sg*4+r)
    f32x4 bqk[4], bvv[2];
#pragma unroll
    for (int t = 0; t < 4; t++) bqk[t] = *(const f32x4*)&biasl[c2 * 64 + t * 16 + sg * 4];
#pragma unroll
    for (int tv = 0; tv < 2; tv++) bvv[tv] = *(const f32x4*)&biasl[128 + c2 * 32 + tv * 16 + sg * 4];

    float vq[4][4];
    float s2 = 0.f, s4 = 0.f;
#pragma unroll
    for (int t = 0; t < 4; t++)
#pragma unroll
      for (int r = 0; r < 4; r++) {
        float y = (fmaxf(aq[t][r] + bqk[t][r], 0.f) + 1e-6f) * inv_denom;
        float y2 = y * y;
        vq[t][r] = y2;
        s2 += y2; s4 += y2 * y2;
      }
    s2 += __shfl_xor(s2, 16); s2 += __shfl_xor(s2, 32);
    s4 += __shfl_xor(s4, 16); s4 += __shfl_xor(s4, 32);
    float sc = sqrtf(s2) / (sqrtf(s4) + 1e-12f);

    {
      u16* sq = stq[buf] + wv * 1152 + m * 72;
#pragma unroll
      for (int t = 0; t < 4; t++)
        *(ushort4*)(sq + ((t + m) & 3) * 16 + sg * 4) =
          cvt4bf(vq[t][0] * sc, vq[t][1] * sc, vq[t][2] * sc, vq[t][3] * sc);
      int rowl = rg * 16 + m;
      u16* sv = stv[buf] + rowl * 72;
#pragma unroll
      for (int tv = 0; tv < 2; tv++) {
        int tc = c2 * 2 + tv;
        f32x4 a = av[tv], b = bvv[tv];
        *(ushort4*)(sv + ((tc + rowl) & 3) * 16 + sg * 4) =
          cvt4bf(a[0] + b[0], a[1] + b[1], a[2] + b[2], a[3] + b[3]);
      }
    }
    // flush q only (phi_k never goes to HBM); wave-local ds order, no barrier
    if (!c2) {
      int r_ = lane >> 2, tc = lane & 3;
      const u16* a = stq[buf] + wv * 1152 + r_ * 72 + ((tc + r_) & 3) * 16;
      s16x8 p0 = *(const s16x8*)a;
      s16x8 p1 = *(const s16x8*)(a + 8);
      int n = n0 + s * 32 + rg * 16 + r_;
      if (n < NROWS) {
        u16* dst = phi_q + ((size_t)h * NROWS + n) * 64 + tc * 16;
        *(s16x8*)dst = p0;
        *(s16x8*)(dst + 8) = p1;
      }
    }
    wg_barrier_lds();   // xs reads + stv/stq writes visible

    // flush v (cross-wave data now visible)
    {
      int row = wv * 8 + (lane >> 3);
      int hc8 = lane & 7, tc = hc8 >> 1, half = hc8 & 1;
      const u16* a = stv[buf] + row * 72 + ((tc + row) & 3) * 16 + half * 8;
      s16x8 pv = *(const s16x8*)a;
      int n = n0 + s * 32 + row;
      if (n < NROWS)
        *(s16x8*)(vout + ((size_t)h * NROWS + n) * 64 + tc * 16 + half * 8) = pv;
    }
    // write xs for s+1 from prefetched regs
    if (s + 1 < NSUB) {
#pragma unroll
      for (int i = 0; i < 4; i++) {
        int cu = tid + i * 256;
        int row = cu >> 5, c = cu & 31;
        float4 f0 = xl[i * 2], f1 = xl[i * 2 + 1];
        union { unsigned u[4]; s16x8 v; } pk;
        pk.u[0] = cvt2bf(f0.x, f0.y);
        pk.u[1] = cvt2bf(f0.z, f0.w);
        pk.u[2] = cvt2bf(f1.x, f1.y);
        pk.u[3] = cvt2bf(f1.z, f1.w);
        *(s16x8*)(xs + row * 256 + ((c ^ (row & 7)) * 8)) = pk.v;
      }
    }
    wg_barrier_lds();   // new xs visible; buf[s-1] safe to overwrite next iter
  }

  // drain: accumulate the last subtile
  if (n0 + (NSUB - 1) * 32 < NROWS) KTV_ACC((NSUB - 1) & 1);

  // write partial kTv^T (d-major) + sum_k row: P[rc][h][65][64]
  // (identical to round-2's harness-PASSED write)
  {
    float* pb = P + (size_t)(rc * NH + h) * (65 * 64);
    int mm = wv * 16 + sg * 4;
#pragma unroll
    for (int dcb = 0; dcb < 4; dcb++)
#pragma unroll
      for (int r = 0; r < 4; r++)
        pb[(dcb * 16 + m) * 64 + mm + r] = kacc[dcb][r];
    if (m == 0)
#pragma unroll
      for (int r = 0; r < 4; r++)
        pb[64 * 64 + mm + r] = ksum[r];
  }
}

// ---------------------------------------------------------------------------
// Kernel 2.5: reduce partials -> bf16 kTvT[8][65][64]; pack WmP[e][d]=Wm[d][e]
// ---------------------------------------------------------------------------
__global__ __launch_bounds__(256) void k25_pack(
    const float* __restrict__ P, const float* __restrict__ Wm,
    u16* __restrict__ kTvT, u16* __restrict__ WmP)
{
  int idx = blockIdx.x * 256 + threadIdx.x;
  if (idx < NH * 65 * 64) {
    float s = 0.f;
    for (int rcc = 0; rcc < NCH1; rcc++)
      s += P[(size_t)rcc * (NH * 65 * 64) + idx];
    kTvT[idx] = f2bf(s);
  } else if (idx < NH * 65 * 64 + 64 * 64) {
    int j = idx - NH * 65 * 64;
    WmP[j] = f2bf(Wm[(j & 63) * 64 + (j >> 6)]);
  }
}

// ---------------------------------------------------------------------------
// Kernel 3: out = mean_h( (phi_q@kTv[h]) / (phi_q.sum_k[h]+1e-6) )
//           + vbar@Wm + bm; Lorentz lift.  (round-6/7-verified version)
// 512 threads / 128 rows per block.  kTvT+WmP staged once into LDS with
// XOR swizzle; __launch_bounds__(512,2) (NOT (512,4): VGPR-64 spill, r5).
// ---------------------------------------------------------------------------
__global__ __launch_bounds__(512, 2) void k3_out(
    const u16* __restrict__ phi_q, const u16* __restrict__ vin,
    const u16* __restrict__ kTvT, const u16* __restrict__ WmP,
    const float* __restrict__ bm, float* __restrict__ out)
{
  __shared__ u16 kbl[37376];   // kTvT[8*65][64] ++ WmP[64][64], swizzled

  const int tid = threadIdx.x;
  const int wv = tid >> 6, lane = tid & 63;
  const int m = lane & 15, sg = lane >> 4;
  const int n0 = blockIdx.x * 128;
  const int rw = wv * 16;
  const int n = n0 + rw + m;

  for (int i = tid; i < 4672; i += 512) {
    int e0 = i * 8;
    s16x8 val = *(const s16x8*)(kTvT + e0);
    int r = e0 >> 6;
    *(s16x8*)&kbl[e0 ^ ((r & 7) << 3)] = val;
  }
  __syncthreads();

#define KBL_FRAG(rowlin, off) \
  (*(const s16x8*)&kbl[(((rowlin) * 64 + (off)) ^ (((rowlin) & 7) << 3))])

  f32x4 zero4 = {0.f, 0.f, 0.f, 0.f};
  s16x8 zero8 = {0, 0, 0, 0, 0, 0, 0, 0};
  f32x4 osum[4];
#pragma unroll
  for (int t = 0; t < 4; t++) osum[t] = zero4;

  float va[2][8];
#pragma unroll
  for (int ks = 0; ks < 2; ks++)
#pragma unroll
    for (int j = 0; j < 8; j++) va[ks][j] = 0.f;

  s16x8 aqn[2];
#pragma unroll
  for (int ks = 0; ks < 2; ks++)
    aqn[ks] = *(const s16x8*)(phi_q + (size_t)n * 64 + ks * 32 + sg * 8);

  for (int h = 0; h < NH; h++) {
    s16x8 aq0 = aqn[0], aq1 = aqn[1];
    s16x8 v80 = *(const s16x8*)(vin + (size_t)h * (NROWS * 64) + (size_t)n * 64 + sg * 8);
    s16x8 v81 = *(const s16x8*)(vin + (size_t)h * (NROWS * 64) + (size_t)n * 64 + 32 + sg * 8);
    if (h + 1 < NH) {
      const u16* pq = phi_q + (size_t)(h + 1) * (NROWS * 64) + (size_t)n * 64;
      aqn[0] = *(const s16x8*)(pq + sg * 8);
      aqn[1] = *(const s16x8*)(pq + 32 + sg * 8);
    }

    const int rl = h * 65;
    f32x4 accn[4];
#pragma unroll
    for (int t = 0; t < 4; t++) accn[t] = zero4;
    f32x4 accd = zero4;
    {
#pragma unroll
      for (int t = 0; t < 4; t++) {
        s16x8 bfv = KBL_FRAG(rl + t * 16 + m, sg * 8);
        accn[t] = __builtin_amdgcn_mfma_f32_16x16x32_bf16(aq0, bfv, accn[t], 0, 0, 0);
      }
      s16x8 bd = zero8;
      if (m == 0) bd = KBL_FRAG(rl + 64, sg * 8);
      accd = __builtin_amdgcn_mfma_f32_16x16x32_bf16(aq0, bd, accd, 0, 0, 0);
    }
    {
#pragma unroll
      for (int t = 0; t < 4; t++) {
        s16x8 bfv = KBL_FRAG(rl + t * 16 + m, 32 + sg * 8);
        accn[t] = __builtin_amdgcn_mfma_f32_16x16x32_bf16(aq1, bfv, accn[t], 0, 0, 0);
      }
      s16x8 bd = zero8;
      if (m == 0) bd = KBL_FRAG(rl + 64, 32 + sg * 8);
      accd = __builtin_amdgcn_mfma_f32_16x16x32_bf16(aq1, bd, accd, 0, 0, 0);
    }

#pragma unroll
    for (int j = 0; j < 8; j++) va[0][j] += bf2f((u16)v80[j]);
#pragma unroll
    for (int j = 0; j < 8; j++) va[1][j] += bf2f((u16)v81[j]);

#pragma unroll
    for (int r = 0; r < 4; r++) {
      float den = __shfl(accd[r], lane & 48);
      float rinv = 1.0f / (den + 1e-6f);
#pragma unroll
      for (int t = 0; t < 4; t++) osum[t][r] += accn[t][r] * rinv;
    }
  }

  s16x8 vbf[2];
#pragma unroll
  for (int ks = 0; ks < 2; ks++) {
    union { unsigned u[4]; s16x8 v; } pk;
#pragma unroll
    for (int j = 0; j < 4; j++)
      pk.u[j] = cvt2bf(va[ks][2 * j] * 0.125f, va[ks][2 * j + 1] * 0.125f);
    vbf[ks] = pk.v;
  }

  f32x4 accr[4];
#pragma unroll
  for (int t = 0; t < 4; t++) accr[t] = zero4;
#pragma unroll
  for (int ks = 0; ks < 2; ks++)
#pragma unroll
    for (int t = 0; t < 4; t++) {
      s16x8 bw = KBL_FRAG(520 + t * 16 + m, ks * 32 + sg * 8);
      accr[t] = __builtin_amdgcn_mfma_f32_16x16x32_bf16(vbf[ks], bw, accr[t], 0, 0, 0);
    }

  float bmv[4];
#pragma unroll
  for (int t = 0; t < 4; t++) bmv[t] = bm[t * 16 + m];

#pragma unroll
  for (int r = 0; r < 4; r++) {
    int nn = n0 + rw + sg * 4 + r;
    float v4[4];
    float ssq = 0.f;
#pragma unroll
    for (int t = 0; t < 4; t++) {
      float o = osum[t][r] * 0.125f + accr[t][r] + bmv[t];
      v4[t] = o;
      ssq += o * o;
    }
    ssq += __shfl_xor(ssq, 1);
    ssq += __shfl_xor(ssq, 2);
    ssq += __shfl_xor(ssq, 4);
    ssq += __shfl_xor(ssq, 8);
    if (nn < NROWS) {
      if (m == 0) out[(size_t)nn * 65] = sqrtf(ssq + 1.0f);
#pragma unroll
      for (int t = 0; t < 4; t++)
        out[(size_t)nn * 65 + 1 + t * 16 + m] = v4[t];
    }
  }
}

// ---------------------------------------------------------------------------
extern "C" void kernel_launch(void* const* d_in, const int* in_sizes, int n_in,
                              void* d_out, int out_size, void* d_ws, size_t ws_size,
                              hipStream_t stream) {
  const float* x   = (const float*)d_in[0];
  const float* Wq  = (const float*)d_in[1];
  const float* bq  = (const float*)d_in[2];
  const float* Wk  = (const float*)d_in[3];
  const float* bk  = (const float*)d_in[4];
  const float* Wv  = (const float*)d_in[5];
  const float* bv  = (const float*)d_in[6];
  const float* nsc = (const float*)d_in[7];
  const float* Wm  = (const float*)d_in[8];
  const float* bm  = (const float*)d_in[9];
  float* out = (float*)d_out;

  char* ws = (char*)d_ws;
  const size_t PHI_BYTES = (size_t)NROWS * NH * 64 * 2;   // 102,400,000
  u16* phi_q = (u16*)(ws);
  u16* vv    = (u16*)(ws + PHI_BYTES);
  u16* Wp    = (u16*)(ws + 2 * PHI_BYTES);                // 786,432 B
  char* p    = ws + 2 * PHI_BYTES + 786432;
  float* P   = (float*)(p);                               // 64*8*65*64*4 = 8,519,680 B
  u16* kTvT  = (u16*)(p + 8519680);                       // 66,560 B
  u16* WmP   = (u16*)(p + 8519680 + 66560);               // 8,192 B (contiguous after kTvT)

  k0_pack<<<192, 256, 0, stream>>>(Wq, Wk, Wv, Wp);
  k1_gemm_phi<<<512, 256, 0, stream>>>(x, Wp, bq, bk, bv, nsc, phi_q, vv, P);
  k25_pack<<<(NH * 65 * 64 + 64 * 64 + 255) / 256, 256, 0, stream>>>(P, Wm, kTvT, WmP);
  k3_out<<<(NROWS + 127) / 128, 512, 0, stream>>>(phi_q, vv, kTvT, WmP, bm, out);
}

// Round 10
// 392.527 us; speedup vs baseline: 1.3817x; 1.3817x over previous
//
#include <hip/hip_runtime.h>
#include <hip/hip_bf16.h>

#define NROWS 100000
#define NH 8
#define RPC 1568     // k1 rows per chunk (64 chunks)
#define NSUB 49      // 32-row subtiles per chunk
#define K2CH 98      // k2 chunks of 1024 rows

typedef short s16x8 __attribute__((ext_vector_type(8)));
typedef float f32x4 __attribute__((ext_vector_type(4)));
typedef unsigned short u16;

__device__ __forceinline__ u16 f2bf(float f) {
  union { float f; unsigned u; } x; x.f = f;
  unsigned r = (x.u + 0x7FFFu + ((x.u >> 16) & 1u)) >> 16;
  return (u16)r;
}
__device__ __forceinline__ float bf2f(u16 b) {
  union { unsigned u; float f; } x; x.u = ((unsigned)b) << 16;
  return x.f;
}
// HW packed f32->bf16 (RNE, bit-identical to f2bf for finite inputs).
__device__ __forceinline__ unsigned cvt2bf(float lo, float hi) {
  unsigned r;
  asm("v_cvt_pk_bf16_f32 %0, %1, %2" : "=v"(r) : "v"(lo), "v"(hi));
  return r;
}
__device__ __forceinline__ ushort4 cvt4bf(float a, float b, float c, float d) {
  union { unsigned u[2]; ushort4 s; } r;
  r.u[0] = cvt2bf(a, b);
  r.u[1] = cvt2bf(c, d);
  return r.s;
}

// Workgroup barrier WITHOUT vmcnt(0) drain: LDS visibility only (r8-verified
// in k1).  Critical for k2's 2-deep prefetch: keeps global loads in flight
// across the barrier (T4 pattern) — __syncthreads' vmcnt(0) would collapse
// the pipeline back to 1-subtile latency exposure.
__device__ __forceinline__ void wg_barrier_lds() {
  asm volatile("s_waitcnt lgkmcnt(0)" ::: "memory");
  __builtin_amdgcn_s_barrier();
  asm volatile("" ::: "memory");
}

// ---------------------------------------------------------------------------
// Kernel 0: pack W to bf16 MFMA A-fragments.
// ---------------------------------------------------------------------------
__global__ __launch_bounds__(256) void k0_pack(
    const float* __restrict__ Wq, const float* __restrict__ Wk,
    const float* __restrict__ Wv, u16* __restrict__ Wp)
{
  int t = blockIdx.x * 256 + threadIdx.x;   // 0..49151
  int lane = t & 63;
  int rest = t >> 6;
  int s = rest % 48;
  int hc = rest / 48;
  int c2 = hc & 1, h = hc >> 1;
  int ml = lane & 15, sgk = lane >> 4;
  const float* W; int col, ks;
  if (s < 32) { int tl = s >> 3; ks = s & 7; W = c2 ? Wk : Wq; col = tl * 16 + ml; }
  else        { int tv = (s >> 3) - 4; ks = s & 7; W = Wv; col = c2 * 32 + tv * 16 + ml; }
  int k0 = ks * 32 + sgk * 8;
  u16 o[8];
#pragma unroll
  for (int j = 0; j < 8; j++)
    o[j] = f2bf(W[((size_t)h * 256 + k0 + j) * 64 + col]);
  ushort4* dst = (ushort4*)(Wp + (size_t)t * 8);
  dst[0] = make_ushort4(o[0], o[1], o[2], o[3]);
  dst[1] = make_ushort4(o[4], o[5], o[6], o[7]);
}

// ---------------------------------------------------------------------------
// Kernel 1: persistent per-head blocks (round-8 version, k1=161.6us).
// Grid 512 = 8 heads x 64 row-chunks, blockIdx = rc + 64*h.  W(q|k) resident
// in regs; W(v) in LDS.  32-row subtiles, x prefetched one subtile ahead.
// cvt_pk epilogues; lgkm-only in-loop barriers.
// ---------------------------------------------------------------------------
__global__ __launch_bounds__(256, 2) void k1_gemm_phi(
    const float* __restrict__ x, const u16* __restrict__ Wp,
    const float* __restrict__ bq, const float* __restrict__ bk,
    const float* __restrict__ bv, const float* __restrict__ nsc,
    u16* __restrict__ phi_q, u16* __restrict__ phi_k, u16* __restrict__ vout)
{
  __shared__ u16 xs[32 * 256];        // 16 KB, chunk-swizzled
  __shared__ u16 vws[32 * 64 * 8];    // 32 KB, v W-fragments
  __shared__ u16 stq[4 * 16 * 72];    // 9216 B, wave-local q/k store staging
  __shared__ u16 stv[32 * 72];        // 4608 B, cross-wave v store staging
  __shared__ float biasl[192];        // [q|k|v]

  const int tid = threadIdx.x;
  const int wv = tid >> 6, lane = tid & 63;
  const int c2 = wv & 1, rg = wv >> 1;
  const int m = lane & 15, sg = lane >> 4;
  const int rc = blockIdx.x & 63, h = blockIdx.x >> 6;
  const int n0 = rc * RPC;

  if (tid < 192) {
    const float* bp = tid < 64 ? bq : (tid < 128 ? bk : bv);
    biasl[tid] = bp[h * 64 + (tid & 63)];
  }

  // resident qk W fragments: 32 x s16x8 = 128 VGPR
  const u16* wb = Wp + (size_t)(h * 2 + c2) * (48 * 64 * 8);
  s16x8 wq[4][8];
#pragma unroll
  for (int t = 0; t < 4; t++)
#pragma unroll
    for (int ks = 0; ks < 8; ks++)
      wq[t][ks] = *(const s16x8*)(wb + ((t * 8 + ks) * 64 + lane) * 8);

  // v W fragments -> LDS (tiles 0..3 across both c2 regions)
#pragma unroll
  for (int i2 = 0; i2 < 8; i2++) {
    int u = tid + i2 * 256;           // 0..2047 = (tl*8+ks)*64 + ln
    int tl = u >> 9, ks = (u >> 6) & 7, ln = u & 63;
    const u16* src = Wp + ((size_t)(h * 2 + (tl >> 1)) * 48 + 32 + (tl & 1) * 8 + ks) * (64 * 8)
                     + (size_t)ln * 8;
    *(s16x8*)(vws + (size_t)u * 8) = *(const s16x8*)src;
  }

  // stage subtile 0
#pragma unroll
  for (int i = 0; i < 4; i++) {
    int cu = tid + i * 256;
    int row = cu >> 5, c = cu & 31;
    int n = n0 + row; if (n >= NROWS) n = NROWS - 1;
    const float* src = x + (size_t)n * 256 + c * 8;
    float4 f0 = *(const float4*)src;
    float4 f1 = *(const float4*)(src + 4);
    union { unsigned u[4]; s16x8 v; } pk;
    pk.u[0] = cvt2bf(f0.x, f0.y);
    pk.u[1] = cvt2bf(f0.z, f0.w);
    pk.u[2] = cvt2bf(f1.x, f1.y);
    pk.u[3] = cvt2bf(f1.z, f1.w);
    *(s16x8*)(xs + row * 256 + ((c ^ (row & 7)) * 8)) = pk.v;
  }
  __syncthreads();

  const float inv_denom = 1.0f / (fabsf(nsc[0]) + 1e-6f);
  u16* const xbase = xs + (rg * 16 + m) * 256;
  const int sw = m & 7;

  for (int s = 0; s < NSUB; s++) {
    // issue x loads for s+1 (regs; consumed after the barrier)
    float4 xl[8];
    if (s + 1 < NSUB) {
      int nb = n0 + (s + 1) * 32;
#pragma unroll
      for (int i = 0; i < 4; i++) {
        int cu = tid + i * 256;
        int row = cu >> 5, c = cu & 31;
        int n = nb + row; if (n >= NROWS) n = NROWS - 1;
        const float* src = x + (size_t)n * 256 + c * 8;
        xl[i * 2]     = *(const float4*)src;
        xl[i * 2 + 1] = *(const float4*)(src + 4);
      }
    }

    // MFMA: 4 qk tiles (resident W) + 2 v tiles (LDS W)
    f32x4 aq[4], av[2];
#pragma unroll
    for (int t = 0; t < 4; t++) aq[t] = (f32x4){0.f, 0.f, 0.f, 0.f};
    av[0] = (f32x4){0.f, 0.f, 0.f, 0.f};
    av[1] = (f32x4){0.f, 0.f, 0.f, 0.f};
#pragma unroll
    for (int ks = 0; ks < 8; ks++) {
      s16x8 bf = *(const s16x8*)(xbase + (((ks * 4 + sg) ^ sw) * 8));
#pragma unroll
      for (int t = 0; t < 4; t++)
        aq[t] = __builtin_amdgcn_mfma_f32_16x16x32_bf16(wq[t][ks], bf, aq[t], 0, 0, 0);
      s16x8 vw0 = *(const s16x8*)(vws + (((c2 * 2 + 0) * 8 + ks) * 64 + lane) * 8);
      s16x8 vw1 = *(const s16x8*)(vws + (((c2 * 2 + 1) * 8 + ks) * 64 + lane) * 8);
      av[0] = __builtin_amdgcn_mfma_f32_16x16x32_bf16(vw0, bf, av[0], 0, 0, 0);
      av[1] = __builtin_amdgcn_mfma_f32_16x16x32_bf16(vw1, bf, av[1], 0, 0, 0);
    }

    // epilogue: bias + phi + in-wave norm (row = rg*16+m, ch = t*16+sg*4+r)
    f32x4 bqk[4], bvv[2];
#pragma unroll
    for (int t = 0; t < 4; t++) bqk[t] = *(const f32x4*)&biasl[c2 * 64 + t * 16 + sg * 4];
#pragma unroll
    for (int tv = 0; tv < 2; tv++) bvv[tv] = *(const f32x4*)&biasl[128 + c2 * 32 + tv * 16 + sg * 4];

    float vq[4][4];
    float s2 = 0.f, s4 = 0.f;
#pragma unroll
    for (int t = 0; t < 4; t++)
#pragma unroll
      for (int r = 0; r < 4; r++) {
        float y = (fmaxf(aq[t][r] + bqk[t][r], 0.f) + 1e-6f) * inv_denom;
        float y2 = y * y;
        vq[t][r] = y2;
        s2 += y2; s4 += y2 * y2;
      }
    s2 += __shfl_xor(s2, 16); s2 += __shfl_xor(s2, 32);
    s4 += __shfl_xor(s4, 16); s4 += __shfl_xor(s4, 32);
    float sc = sqrtf(s2) / (sqrtf(s4) + 1e-12f);

    {
      u16* sq = stq + wv * 1152 + m * 72;
#pragma unroll
      for (int t = 0; t < 4; t++)
        *(ushort4*)(sq + ((t + m) & 3) * 16 + sg * 4) =
          cvt4bf(vq[t][0] * sc, vq[t][1] * sc, vq[t][2] * sc, vq[t][3] * sc);
      int rowl = rg * 16 + m;
      u16* sv = stv + rowl * 72;
#pragma unroll
      for (int tv = 0; tv < 2; tv++) {
        int tc = c2 * 2 + tv;
        f32x4 a = av[tv], b = bvv[tv];
        *(ushort4*)(sv + ((tc + rowl) & 3) * 16 + sg * 4) =
          cvt4bf(a[0] + b[0], a[1] + b[1], a[2] + b[2], a[3] + b[3]);
      }
    }
    // flush q/k (wave-local: same-wave ds_write->ds_read, no barrier)
    {
      int r_ = lane >> 2, tc = lane & 3;
      const u16* a = stq + wv * 1152 + r_ * 72 + ((tc + r_) & 3) * 16;
      s16x8 p0 = *(const s16x8*)a;
      s16x8 p1 = *(const s16x8*)(a + 8);
      int n = n0 + s * 32 + rg * 16 + r_;
      if (n < NROWS) {
        u16* dst = (c2 ? phi_k : phi_q) + ((size_t)h * NROWS + n) * 64 + tc * 16;
        *(s16x8*)dst = p0;
        *(s16x8*)(dst + 8) = p1;
      }
    }
    wg_barrier_lds();   // xs reads + stv writes visible; stores NOT drained

    // flush v (cross-wave data now visible)
    {
      int row = wv * 8 + (lane >> 3);
      int hc8 = lane & 7, tc = hc8 >> 1, half = hc8 & 1;
      const u16* a = stv + row * 72 + ((tc + row) & 3) * 16 + half * 8;
      s16x8 pv = *(const s16x8*)a;
      int n = n0 + s * 32 + row;
      if (n < NROWS)
        *(s16x8*)(vout + ((size_t)h * NROWS + n) * 64 + tc * 16 + half * 8) = pv;
    }
    // write xs for s+1 from prefetched regs
    if (s + 1 < NSUB) {
#pragma unroll
      for (int i = 0; i < 4; i++) {
        int cu = tid + i * 256;
        int row = cu >> 5, c = cu & 31;
        float4 f0 = xl[i * 2], f1 = xl[i * 2 + 1];
        union { unsigned u[4]; s16x8 v; } pk;
        pk.u[0] = cvt2bf(f0.x, f0.y);
        pk.u[1] = cvt2bf(f0.z, f0.w);
        pk.u[2] = cvt2bf(f1.x, f1.y);
        pk.u[3] = cvt2bf(f1.z, f1.w);
        *(s16x8*)(xs + row * 256 + ((c ^ (row & 7)) * 8)) = pk.v;
      }
    }
    wg_barrier_lds();   // new xs visible; stv flushed before next overwrite
  }
}

// ---------------------------------------------------------------------------
// Kernel 2 (REWRITTEN): partial kT_v per 1024-row chunk.
// Fixes vs round-0 version (which ran ~110us for 33us of traffic):
// 1) LDS transpose-write bank conflicts: [64][72] u16 has row*36 mod 32
//    collapsing to banks {0,16} -> ushort4 writes were ~8-way.  Column
//    XOR-swizzle col ^= ((row>>2)&3)<<3 (write side: constant wsw per
//    thread since row=4*t15+i -> row>>2 = t15; read side: rsw from m>>2).
//    Bank math: writes and reads both become 2-way (free).  16B alignment
//    of b128 reads preserved (XOR touches u16-bits 3..4 only).
// 2) Latency: 2-subtile-deep register prefetch (named A/B buffers,
//    pair-unrolled loop -> static indexing) + lgkm-only barriers so the
//    global loads stay in flight ACROSS barriers.  Old code consumed loads
//    in the same iteration they were issued -> full HBM latency per subtile.
// Arithmetic/layout of P identical to round-0 (harness-verified).
// ---------------------------------------------------------------------------
__global__ __launch_bounds__(256) void k2_ktv(
    const u16* __restrict__ phi_k, const u16* __restrict__ vin,
    float* __restrict__ P)
{
  __shared__ u16 pkT[2][64][72];
  __shared__ u16 vT[2][64][72];
  const int tid = threadIdx.x;
  const int h = blockIdx.y;
  const int r0 = blockIdx.x * 1024;
  const int wv = tid >> 6, lane = tid & 63;
  const int m = lane & 15, sg = lane >> 4;
  const int t15 = tid & 15, rgp = tid >> 4;
  const int c4 = t15 * 4;
  const int wsw = (rgp * 4) ^ ((t15 & 3) << 3);   // swizzled write col
  const int rsw = (m >> 2) << 3;                  // read col XOR

  const u16* pkb = phi_k + (size_t)h * (NROWS * 64);
  const u16* vb  = vin  + (size_t)h * (NROWS * 64);

  f32x4 acc[4];
#pragma unroll
  for (int t = 0; t < 4; t++) acc[t] = (f32x4){0.f, 0.f, 0.f, 0.f};
  f32x4 accs = (f32x4){0.f, 0.f, 0.f, 0.f};
  s16x8 onesf;
#pragma unroll
  for (int j = 0; j < 8; j++) onesf[j] = (m == 0) ? (short)0x3F80 : (short)0;

  ushort4 pkA[4], vvA[4], pkB[4], vvB[4];

#define K2_LOAD(dP, dV, sub)                                                \
  {                                                                         \
    int nb = r0 + (sub) * 64 + rgp * 4;                                     \
    _Pragma("unroll")                                                       \
    for (int i = 0; i < 4; i++) {                                           \
      int n = nb + i;                                                       \
      if (n < NROWS) {                                                      \
        dP[i] = *(const ushort4*)(pkb + (size_t)n * 64 + c4);               \
        dV[i] = *(const ushort4*)(vb  + (size_t)n * 64 + c4);               \
      } else {                                                              \
        dP[i] = make_ushort4(0, 0, 0, 0);                                   \
        dV[i] = make_ushort4(0, 0, 0, 0);                                   \
      }                                                                     \
    }                                                                       \
  }
#define K2_WRITE(buf, sP, sV)                                               \
  {                                                                         \
    *(ushort4*)&pkT[buf][c4 + 0][wsw] = make_ushort4(sP[0].x, sP[1].x, sP[2].x, sP[3].x); \
    *(ushort4*)&pkT[buf][c4 + 1][wsw] = make_ushort4(sP[0].y, sP[1].y, sP[2].y, sP[3].y); \
    *(ushort4*)&pkT[buf][c4 + 2][wsw] = make_ushort4(sP[0].z, sP[1].z, sP[2].z, sP[3].z); \
    *(ushort4*)&pkT[buf][c4 + 3][wsw] = make_ushort4(sP[0].w, sP[1].w, sP[2].w, sP[3].w); \
    *(ushort4*)&vT[buf][c4 + 0][wsw]  = make_ushort4(sV[0].x, sV[1].x, sV[2].x, sV[3].x); \
    *(ushort4*)&vT[buf][c4 + 1][wsw]  = make_ushort4(sV[0].y, sV[1].y, sV[2].y, sV[3].y); \
    *(ushort4*)&vT[buf][c4 + 2][wsw]  = make_ushort4(sV[0].z, sV[1].z, sV[2].z, sV[3].z); \
    *(ushort4*)&vT[buf][c4 + 3][wsw]  = make_ushort4(sV[0].w, sV[1].w, sV[2].w, sV[3].w); \
  }
#define K2_MFMA(buf)                                                        \
  {                                                                         \
    _Pragma("unroll")                                                       \
    for (int ks = 0; ks < 2; ks++) {                                        \
      s16x8 af = *(const s16x8*)&pkT[buf][wv * 16 + m][(ks * 32 + sg * 8) ^ rsw]; \
      _Pragma("unroll")                                                     \
      for (int t = 0; t < 4; t++) {                                         \
        s16x8 bfv = *(const s16x8*)&vT[buf][t * 16 + m][(ks * 32 + sg * 8) ^ rsw]; \
        acc[t] = __builtin_amdgcn_mfma_f32_16x16x32_bf16(af, bfv, acc[t], 0, 0, 0); \
      }                                                                     \
      accs = __builtin_amdgcn_mfma_f32_16x16x32_bf16(af, onesf, accs, 0, 0, 0); \
    }                                                                       \
  }

  // prologue: sub0 -> LDS0; sub1 loads in flight
  K2_LOAD(pkA, vvA, 0);
  K2_WRITE(0, pkA, vvA);
  K2_LOAD(pkB, vvB, 1);
  wg_barrier_lds();

  // steady state (pair-unrolled, static A/B): iter s reads LDS[s&1];
  // writes LDS[(s+1)&1] from the buffer loaded 2 iters ago (latency
  // covered); issues loads for s+2.  Barrier is lgkm-only -> loads
  // remain outstanding across it.
#pragma unroll 1
  for (int sp = 0; sp < 8; sp++) {
    int s0 = sp * 2;
    // iter s0: cur = LDS0
    K2_MFMA(0);
    K2_WRITE(1, pkB, vvB);                    // sub s0+1 (always < 16)
    if (s0 + 2 < 16) K2_LOAD(pkA, vvA, s0 + 2);
    wg_barrier_lds();
    // iter s0+1: cur = LDS1
    K2_MFMA(1);
    if (s0 + 2 < 16) K2_WRITE(0, pkA, vvA);   // sub s0+2
    if (s0 + 3 < 16) K2_LOAD(pkB, vvB, s0 + 3);
    wg_barrier_lds();
  }

  float* pb = P + (size_t)(blockIdx.x * NH + h) * (65 * 64);
  int mm = wv * 16 + sg * 4;
#pragma unroll
  for (int t = 0; t < 4; t++)
#pragma unroll
    for (int r = 0; r < 4; r++)
      pb[(t * 16 + m) * 64 + mm + r] = acc[t][r];
  if (m == 0)
#pragma unroll
    for (int r = 0; r < 4; r++)
      pb[64 * 64 + mm + r] = accs[r];
}

// ---------------------------------------------------------------------------
// Kernel 2.5: reduce partials -> bf16 kTvT[8][65][64]; pack WmP[e][d]=Wm[d][e]
// ---------------------------------------------------------------------------
__global__ __launch_bounds__(256) void k25_pack(
    const float* __restrict__ P, const float* __restrict__ Wm,
    u16* __restrict__ kTvT, u16* __restrict__ WmP)
{
  int idx = blockIdx.x * 256 + threadIdx.x;
  if (idx < NH * 65 * 64) {
    float s = 0.f;
    for (int rcc = 0; rcc < K2CH; rcc++)
      s += P[(size_t)rcc * (NH * 65 * 64) + idx];
    kTvT[idx] = f2bf(s);
  } else if (idx < NH * 65 * 64 + 64 * 64) {
    int j = idx - NH * 65 * 64;
    WmP[j] = f2bf(Wm[(j & 63) * 64 + (j >> 6)]);
  }
}

// ---------------------------------------------------------------------------
// Kernel 3: out = mean_h( (phi_q@kTv[h]) / (phi_q.sum_k[h]+1e-6) )
//           + vbar@Wm + bm; Lorentz lift.  (round-7-verified version)
// 512 threads / 128 rows; kTvT+WmP staged once into swizzled LDS;
// __launch_bounds__(512,2) (NOT (512,4): VGPR-64 spill, r5).
// ---------------------------------------------------------------------------
__global__ __launch_bounds__(512, 2) void k3_out(
    const u16* __restrict__ phi_q, const u16* __restrict__ vin,
    const u16* __restrict__ kTvT, const u16* __restrict__ WmP,
    const float* __restrict__ bm, float* __restrict__ out)
{
  __shared__ u16 kbl[37376];   // kTvT[8*65][64] ++ WmP[64][64], swizzled

  const int tid = threadIdx.x;
  const int wv = tid >> 6, lane = tid & 63;
  const int m = lane & 15, sg = lane >> 4;
  const int n0 = blockIdx.x * 128;
  const int rw = wv * 16;
  const int n = n0 + rw + m;

  for (int i = tid; i < 4672; i += 512) {
    int e0 = i * 8;
    s16x8 val = *(const s16x8*)(kTvT + e0);
    int r = e0 >> 6;
    *(s16x8*)&kbl[e0 ^ ((r & 7) << 3)] = val;
  }
  __syncthreads();

#define KBL_FRAG(rowlin, off) \
  (*(const s16x8*)&kbl[(((rowlin) * 64 + (off)) ^ (((rowlin) & 7) << 3))])

  f32x4 zero4 = {0.f, 0.f, 0.f, 0.f};
  s16x8 zero8 = {0, 0, 0, 0, 0, 0, 0, 0};
  f32x4 osum[4];
#pragma unroll
  for (int t = 0; t < 4; t++) osum[t] = zero4;

  float va[2][8];
#pragma unroll
  for (int ks = 0; ks < 2; ks++)
#pragma unroll
    for (int j = 0; j < 8; j++) va[ks][j] = 0.f;

  s16x8 aqn[2];
#pragma unroll
  for (int ks = 0; ks < 2; ks++)
    aqn[ks] = *(const s16x8*)(phi_q + (size_t)n * 64 + ks * 32 + sg * 8);

  for (int h = 0; h < NH; h++) {
    s16x8 aq0 = aqn[0], aq1 = aqn[1];
    s16x8 v80 = *(const s16x8*)(vin + (size_t)h * (NROWS * 64) + (size_t)n * 64 + sg * 8);
    s16x8 v81 = *(const s16x8*)(vin + (size_t)h * (NROWS * 64) + (size_t)n * 64 + 32 + sg * 8);
    if (h + 1 < NH) {
      const u16* pq = phi_q + (size_t)(h + 1) * (NROWS * 64) + (size_t)n * 64;
      aqn[0] = *(const s16x8*)(pq + sg * 8);
      aqn[1] = *(const s16x8*)(pq + 32 + sg * 8);
    }

    const int rl = h * 65;
    f32x4 accn[4];
#pragma unroll
    for (int t = 0; t < 4; t++) accn[t] = zero4;
    f32x4 accd = zero4;
    {
#pragma unroll
      for (int t = 0; t < 4; t++) {
        s16x8 bfv = KBL_FRAG(rl + t * 16 + m, sg * 8);
        accn[t] = __builtin_amdgcn_mfma_f32_16x16x32_bf16(aq0, bfv, accn[t], 0, 0, 0);
      }
      s16x8 bd = zero8;
      if (m == 0) bd = KBL_FRAG(rl + 64, sg * 8);
      accd = __builtin_amdgcn_mfma_f32_16x16x32_bf16(aq0, bd, accd, 0, 0, 0);
    }
    {
#pragma unroll
      for (int t = 0; t < 4; t++) {
        s16x8 bfv = KBL_FRAG(rl + t * 16 + m, 32 + sg * 8);
        accn[t] = __builtin_amdgcn_mfma_f32_16x16x32_bf16(aq1, bfv, accn[t], 0, 0, 0);
      }
      s16x8 bd = zero8;
      if (m == 0) bd = KBL_FRAG(rl + 64, 32 + sg * 8);
      accd = __builtin_amdgcn_mfma_f32_16x16x32_bf16(aq1, bd, accd, 0, 0, 0);
    }

#pragma unroll
    for (int j = 0; j < 8; j++) va[0][j] += bf2f((u16)v80[j]);
#pragma unroll
    for (int j = 0; j < 8; j++) va[1][j] += bf2f((u16)v81[j]);

#pragma unroll
    for (int r = 0; r < 4; r++) {
      float den = __shfl(accd[r], lane & 48);
      float rinv = 1.0f / (den + 1e-6f);
#pragma unroll
      for (int t = 0; t < 4; t++) osum[t][r] += accn[t][r] * rinv;
    }
  }

  s16x8 vbf[2];
#pragma unroll
  for (int ks = 0; ks < 2; ks++) {
    union { unsigned u[4]; s16x8 v; } pk;
#pragma unroll
    for (int j = 0; j < 4; j++)
      pk.u[j] = cvt2bf(va[ks][2 * j] * 0.125f, va[ks][2 * j + 1] * 0.125f);
    vbf[ks] = pk.v;
  }

  f32x4 accr[4];
#pragma unroll
  for (int t = 0; t < 4; t++) accr[t] = zero4;
#pragma unroll
  for (int ks = 0; ks < 2; ks++)
#pragma unroll
    for (int t = 0; t < 4; t++) {
      s16x8 bw = KBL_FRAG(520 + t * 16 + m, ks * 32 + sg * 8);
      accr[t] = __builtin_amdgcn_mfma_f32_16x16x32_bf16(vbf[ks], bw, accr[t], 0, 0, 0);
    }

  float bmv[4];
#pragma unroll
  for (int t = 0; t < 4; t++) bmv[t] = bm[t * 16 + m];

#pragma unroll
  for (int r = 0; r < 4; r++) {
    int nn = n0 + rw + sg * 4 + r;
    float v4[4];
    float ssq = 0.f;
#pragma unroll
    for (int t = 0; t < 4; t++) {
      float o = osum[t][r] * 0.125f + accr[t][r] + bmv[t];
      v4[t] = o;
      ssq += o * o;
    }
    ssq += __shfl_xor(ssq, 1);
    ssq += __shfl_xor(ssq, 2);
    ssq += __shfl_xor(ssq, 4);
    ssq += __shfl_xor(ssq, 8);
    if (nn < NROWS) {
      if (m == 0) out[(size_t)nn * 65] = sqrtf(ssq + 1.0f);
#pragma unroll
      for (int t = 0; t < 4; t++)
        out[(size_t)nn * 65 + 1 + t * 16 + m] = v4[t];
    }
  }
}

// ---------------------------------------------------------------------------
extern "C" void kernel_launch(void* const* d_in, const int* in_sizes, int n_in,
                              void* d_out, int out_size, void* d_ws, size_t ws_size,
                              hipStream_t stream) {
  const float* x   = (const float*)d_in[0];
  const float* Wq  = (const float*)d_in[1];
  const float* bq  = (const float*)d_in[2];
  const float* Wk  = (const float*)d_in[3];
  const float* bk  = (const float*)d_in[4];
  const float* Wv  = (const float*)d_in[5];
  const float* bv  = (const float*)d_in[6];
  const float* nsc = (const float*)d_in[7];
  const float* Wm  = (const float*)d_in[8];
  const float* bm  = (const float*)d_in[9];
  float* out = (float*)d_out;

  char* ws = (char*)d_ws;
  const size_t PHI_BYTES = (size_t)NROWS * NH * 64 * 2;   // 102,400,000
  u16* phi_q = (u16*)(ws);
  u16* phi_k = (u16*)(ws + PHI_BYTES);
  u16* vv    = (u16*)(ws + 2 * PHI_BYTES);
  u16* Wp    = (u16*)(ws + 3 * PHI_BYTES);                // 786,432 B
  char* p    = ws + 3 * PHI_BYTES + 786432;
  float* P   = (float*)(p);                               // 98*8*65*64*4 = 13,066,240 B
  u16* kTvT  = (u16*)(p + 13066240);                      // 66,560 B
  u16* WmP   = (u16*)(p + 13066240 + 66560);              // 8,192 B (contiguous after kTvT)

  k0_pack<<<192, 256, 0, stream>>>(Wq, Wk, Wv, Wp);
  k1_gemm_phi<<<512, 256, 0, stream>>>(x, Wp, bq, bk, bv, nsc, phi_q, phi_k, vv);
  dim3 g2(K2CH, NH);
  k2_ktv<<<g2, 256, 0, stream>>>(phi_k, vv, P);
  k25_pack<<<(NH * 65 * 64 + 64 * 64 + 255) / 256, 256, 0, stream>>>(P, Wm, kTvT, WmP);
  k3_out<<<(NROWS + 127) / 128, 512, 0, stream>>>(phi_q, vv, kTvT, WmP, bm, out);
}